// Round 1
// baseline (661.275 us; speedup 1.0000x reference)
//
#include <hip/hip_runtime.h>

#define N_NODES 100000
#define N_EDGES 1600000

// ---------------- JAX threefry2x32 (partitionable scheme) ----------------
struct U2 { unsigned a, b; };

__host__ __device__ constexpr U2 tf2x32(unsigned k0, unsigned k1, unsigned c0, unsigned c1) {
  unsigned ks2 = k0 ^ k1 ^ 0x1BD11BDAu;
  unsigned x0 = c0 + k0, x1 = c1 + k1;
#define TFR(r) { x0 += x1; x1 = (x1 << (r)) | (x1 >> (32 - (r))); x1 ^= x0; }
  TFR(13) TFR(15) TFR(26) TFR(6)
  x0 += k1;  x1 += ks2 + 1u;
  TFR(17) TFR(29) TFR(16) TFR(24)
  x0 += ks2; x1 += k0 + 2u;
  TFR(13) TFR(15) TFR(26) TFR(6)
  x0 += k0;  x1 += k1 + 3u;
  TFR(17) TFR(29) TFR(16) TFR(24)
  x0 += k1;  x1 += ks2 + 4u;
  TFR(13) TFR(15) TFR(26) TFR(6)
  x0 += ks2; x1 += k0 + 5u;
#undef TFR
  return U2{x0, x1};
}

// jax.random.split(jax.random.key(42), 2) under jax_threefry_partitionable=True:
// dk[i] = threefry2x32(key=(0,42), counter=(0,i))
constexpr U2 DK0 = tf2x32(0u, 42u, 0u, 0u);
constexpr U2 DK1 = tf2x32(0u, 42u, 0u, 1u);

// random_bits(32) partitionable: bits[j] = w0 ^ w1 of threefry(key,(0,j)).
// bernoulli keep (p=0.5): uniform = bitcast((bits>>9)|0x3f800000)-1 < 0.5
//                         <=> top bit of bits is 0.
__device__ __forceinline__ bool keep_bit(unsigned k0, unsigned k1, unsigned j) {
  U2 w = tf2x32(k0, k1, 0u, j);
  return ((w.a ^ w.b) >> 31) == 0u;
}

// ---------------- Kernel A: xl = x@W1_l, xr = x@W1_r (wave per row) -------
__global__ __launch_bounds__(256) void k_transform1(
    const float* __restrict__ x, const float* __restrict__ Wl,
    const float* __restrict__ Wr, float* __restrict__ xl,
    float* __restrict__ xr) {
  int wid = (int)((blockIdx.x * blockDim.x + threadIdx.x) >> 6);
  int lane = threadIdx.x & 63;
  if (wid >= N_NODES) return;
  float xv = x[wid * 64 + lane];               // full 64-wide row, coalesced
  const float* W = (lane < 32) ? Wl : Wr;      // half-wave per output matrix
  int c = lane & 31;
  float s = 0.f;
#pragma unroll
  for (int k = 0; k < 64; ++k) {
    float b = __shfl(xv, k, 64);
    s += b * W[k * 32 + c];
  }
  if (lane < 32) xl[wid * 32 + c] = s;
  else           xr[wid * 32 + c] = s;
}

// ---------------- Kernel B/D: edge scatter-add (32 lanes per edge) --------
__global__ __launch_bounds__(256) void k_aggregate(
    const float* __restrict__ feat, const int* __restrict__ src,
    const int* __restrict__ dst, float* __restrict__ agg,
    float* __restrict__ cnt) {
  long long tid = (long long)blockIdx.x * blockDim.x + threadIdx.x;
  int e = (int)(tid >> 5);
  int c = (int)(tid & 31);
  if (e >= N_EDGES) return;
  int s = src[e];
  int d = dst[e];
  float v = feat[s * 32 + c];                  // coalesced 128B row gather
  unsafeAtomicAdd(&agg[d * 32 + c], v);        // hw global_atomic_add_f32
  if (cnt != nullptr && c == 0) unsafeAtomicAdd(&cnt[d], 1.0f);
}

// ---------------- Kernel C: h' = dropout(lrelu(agg1/cnt + b1 + xr)) -------
__global__ __launch_bounds__(256) void k_h1(
    const float* __restrict__ agg1, const float* __restrict__ xr,
    const float* __restrict__ cnt, const float* __restrict__ b1,
    float* __restrict__ hp) {
  int j = (int)(blockIdx.x * blockDim.x + threadIdx.x);
  if (j >= N_NODES * 32) return;
  int i = j >> 5, c = j & 31;
  float inv = 1.0f / fmaxf(cnt[i], 1.0f);
  float v = agg1[j] * inv + b1[c] + xr[j];
  v = (v > 0.f) ? v : 0.01f * v;               // leaky_relu
  hp[j] = keep_bit(DK0.a, DK0.b, (unsigned)j) ? 2.0f * v : 0.0f;
}

// ---- Kernel E: out = l2norm(dropout(agg2/cnt @ W2l + b2 + h' @ W2r)) -----
__global__ __launch_bounds__(256) void k_out(
    const float* __restrict__ agg2, const float* __restrict__ hp,
    const float* __restrict__ cnt, const float* __restrict__ W2l,
    const float* __restrict__ b2, const float* __restrict__ W2r,
    float* __restrict__ out) {
  int wid = (int)((blockIdx.x * blockDim.x + threadIdx.x) >> 6);
  int lane = threadIdx.x & 63;
  if (wid >= N_NODES) return;
  // lanes 0..31 hold agg2 row, lanes 32..63 hold h' row (both 32 wide)
  float rv = (lane < 32) ? agg2[wid * 32 + lane] : hp[wid * 32 + (lane - 32)];
  float s1 = 0.f, s2 = 0.f;
#pragma unroll
  for (int k = 0; k < 32; ++k) {
    float a = __shfl(rv, k, 64);
    float h = __shfl(rv, 32 + k, 64);
    s1 += a * W2l[k * 64 + lane];
    s2 += h * W2r[k * 64 + lane];
  }
  float inv = 1.0f / fmaxf(cnt[wid], 1.0f);
  float v = s1 * inv + b2[lane] + s2;
  unsigned j = (unsigned)(wid * 64 + lane);
  float d = keep_bit(DK1.a, DK1.b, j) ? 2.0f * v : 0.0f;
  float ss = d * d;
#pragma unroll
  for (int o = 32; o > 0; o >>= 1) ss += __shfl_xor(ss, o, 64);
  float scale = 1.0f / fmaxf(sqrtf(ss), 1e-12f);
  out[j] = d * scale;
}

// --------------------------------------------------------------------------
extern "C" void kernel_launch(void* const* d_in, const int* in_sizes, int n_in,
                              void* d_out, int out_size, void* d_ws, size_t ws_size,
                              hipStream_t stream) {
  const float* x   = (const float*)d_in[0];
  const int*   ei  = (const int*)d_in[1];   // int64 in ref, harness delivers int32
  const float* W1l = (const float*)d_in[2];
  const float* b1  = (const float*)d_in[3];
  const float* W1r = (const float*)d_in[4];
  const float* W2l = (const float*)d_in[5];
  const float* b2  = (const float*)d_in[6];
  const float* W2r = (const float*)d_in[7];
  float* out = (float*)d_out;

  const int* src = ei;            // edge_index[0]
  const int* dst = ei + N_EDGES;  // edge_index[1]

  const size_t F32 = (size_t)N_NODES * 32;
  float* xl   = (float*)d_ws;     // later reused as agg2
  float* xr   = xl + F32;
  float* agg1 = xr + F32;
  float* hp   = agg1 + F32;
  float* cnt  = hp + F32;         // total ~51.7 MB of ws

  hipMemsetAsync(agg1, 0, F32 * sizeof(float), stream);
  hipMemsetAsync(cnt, 0, (size_t)N_NODES * sizeof(float), stream);

  // A: per-row dense transforms (64 -> 32+32)
  k_transform1<<<(N_NODES + 3) / 4, 256, 0, stream>>>(x, W1l, W1r, xl, xr);

  // B: aggregate xl over edges + degree counts
  long long tB = (long long)N_EDGES * 32;
  k_aggregate<<<(unsigned)((tB + 255) / 256), 256, 0, stream>>>(xl, src, dst, agg1, cnt);

  // C: h' (lrelu + dropout mask 1)
  k_h1<<<(N_NODES * 32 + 255) / 256, 256, 0, stream>>>(agg1, xr, cnt, b1, hp);

  // D: aggregate h' into agg2 (reuse xl buffer)
  hipMemsetAsync(xl, 0, F32 * sizeof(float), stream);
  k_aggregate<<<(unsigned)((tB + 255) / 256), 256, 0, stream>>>(hp, src, dst, xl, nullptr);

  // E: output transform + dropout mask 2 + row L2 normalize
  k_out<<<(N_NODES + 3) / 4, 256, 0, stream>>>(xl, hp, cnt, W2l, b2, W2r, out);
}

// Round 2
// 634.615 us; speedup vs baseline: 1.0420x; 1.0420x over previous
//
#include <hip/hip_runtime.h>

#define N_NODES 100000
#define N_EDGES 1600000

// ---------------- JAX threefry2x32 (partitionable scheme) ----------------
struct U2 { unsigned a, b; };

__host__ __device__ constexpr U2 tf2x32(unsigned k0, unsigned k1, unsigned c0, unsigned c1) {
  unsigned ks2 = k0 ^ k1 ^ 0x1BD11BDAu;
  unsigned x0 = c0 + k0, x1 = c1 + k1;
#define TFR(r) { x0 += x1; x1 = (x1 << (r)) | (x1 >> (32 - (r))); x1 ^= x0; }
  TFR(13) TFR(15) TFR(26) TFR(6)
  x0 += k1;  x1 += ks2 + 1u;
  TFR(17) TFR(29) TFR(16) TFR(24)
  x0 += ks2; x1 += k0 + 2u;
  TFR(13) TFR(15) TFR(26) TFR(6)
  x0 += k0;  x1 += k1 + 3u;
  TFR(17) TFR(29) TFR(16) TFR(24)
  x0 += k1;  x1 += ks2 + 4u;
  TFR(13) TFR(15) TFR(26) TFR(6)
  x0 += ks2; x1 += k0 + 5u;
#undef TFR
  return U2{x0, x1};
}

constexpr U2 DK0 = tf2x32(0u, 42u, 0u, 0u);
constexpr U2 DK1 = tf2x32(0u, 42u, 0u, 1u);

__device__ __forceinline__ bool keep_bit(unsigned k0, unsigned k1, unsigned j) {
  U2 w = tf2x32(k0, k1, 0u, j);
  return ((w.a ^ w.b) >> 31) == 0u;
}

// ---------------- Kernel A: xl = x@W1_l, xr = x@W1_r (wave per row) -------
__global__ __launch_bounds__(256) void k_transform1(
    const float* __restrict__ x, const float* __restrict__ Wl,
    const float* __restrict__ Wr, float* __restrict__ xl,
    float* __restrict__ xr) {
  int wid = (int)((blockIdx.x * blockDim.x + threadIdx.x) >> 6);
  int lane = threadIdx.x & 63;
  if (wid >= N_NODES) return;
  float xv = x[wid * 64 + lane];
  const float* W = (lane < 32) ? Wl : Wr;
  int c = lane & 31;
  float s = 0.f;
#pragma unroll
  for (int k = 0; k < 64; ++k) {
    float b = __shfl(xv, k, 64);
    s += b * W[k * 32 + c];
  }
  if (lane < 32) xl[wid * 32 + c] = s;
  else           xr[wid * 32 + c] = s;
}

// ---------------- CSR build ----------------
__global__ __launch_bounds__(256) void k_count(
    const int* __restrict__ dst, int* __restrict__ deg) {
  int e = (int)(blockIdx.x * blockDim.x + threadIdx.x);
  if (e >= N_EDGES) return;
  atomicAdd(&deg[dst[e]], 1);
}

// single-block exclusive scan over deg -> offs and cursor
__global__ __launch_bounds__(1024) void k_scan(
    const int* __restrict__ deg, int* __restrict__ offs,
    int* __restrict__ cursor) {
  __shared__ int warp_sums[16];
  __shared__ int s_running;
  int t = threadIdx.x;
  int lane = t & 63, w = t >> 6;
  if (t == 0) s_running = 0;
  __syncthreads();
  for (int base = 0; base < N_NODES; base += 1024) {
    int i = base + t;
    int v = (i < N_NODES) ? deg[i] : 0;
    int x = v;
#pragma unroll
    for (int o = 1; o < 64; o <<= 1) {
      int y = __shfl_up(x, o, 64);
      if (lane >= o) x += y;
    }
    if (lane == 63) warp_sums[w] = x;
    __syncthreads();
    if (w == 0) {
      int ws = (lane < 16) ? warp_sums[lane] : 0;
#pragma unroll
      for (int o = 1; o < 16; o <<= 1) {
        int y = __shfl_up(ws, o, 64);
        if (lane >= o) ws += y;
      }
      if (lane < 16) warp_sums[lane] = ws;
    }
    __syncthreads();
    int incl = x + (w > 0 ? warp_sums[w - 1] : 0);
    int excl = s_running + incl - v;
    if (i < N_NODES) { offs[i] = excl; cursor[i] = excl; }
    __syncthreads();
    if (t == 1023) s_running += incl;
    __syncthreads();
  }
}

__global__ __launch_bounds__(256) void k_fill(
    const int* __restrict__ src, const int* __restrict__ dst,
    int* __restrict__ cursor, int* __restrict__ eidx) {
  int e = (int)(blockIdx.x * blockDim.x + threadIdx.x);
  if (e >= N_EDGES) return;
  int d = dst[e];
  int p = atomicAdd(&cursor[d], 1);
  eidx[p] = src[e];
}

// ---- Gather layer 1: hp = dropout(lrelu(mean(xl[nbrs]) + b1 + xr)) ------
__global__ __launch_bounds__(256) void k_gather1(
    const float* __restrict__ xl, const float* __restrict__ xr,
    const int* __restrict__ offs, const int* __restrict__ deg,
    const int* __restrict__ eidx, const float* __restrict__ b1,
    float* __restrict__ hp) {
  int wid = (int)((blockIdx.x * blockDim.x + threadIdx.x) >> 6);
  int lane = threadIdx.x & 63;
  if (wid >= N_NODES) return;
  int c = lane & 31, half = lane >> 5;
  int off = offs[wid];
  int dg = deg[wid];
  float acc = 0.f;
  for (int k = half; k < dg; k += 2) {
    int s = eidx[off + k];
    acc += xl[s * 32 + c];
  }
  acc += __shfl_xor(acc, 32, 64);
  if (lane < 32) {
    float inv = 1.0f / fmaxf((float)dg, 1.0f);
    int j = wid * 32 + c;
    float v = acc * inv + b1[c] + xr[j];
    v = (v > 0.f) ? v : 0.01f * v;
    hp[j] = keep_bit(DK0.a, DK0.b, (unsigned)j) ? 2.0f * v : 0.0f;
  }
}

// ---- Gather layer 2 fused with output GEMM + dropout + L2 norm ----------
__global__ __launch_bounds__(256) void k_out(
    const float* __restrict__ hp, const int* __restrict__ offs,
    const int* __restrict__ deg, const int* __restrict__ eidx,
    const float* __restrict__ W2l, const float* __restrict__ b2,
    const float* __restrict__ W2r, float* __restrict__ out) {
  int wid = (int)((blockIdx.x * blockDim.x + threadIdx.x) >> 6);
  int lane = threadIdx.x & 63;
  if (wid >= N_NODES) return;
  int c = lane & 31, half = lane >> 5;
  int off = offs[wid];
  int dg = deg[wid];
  float acc = 0.f;
  for (int k = half; k < dg; k += 2) {
    int s = eidx[off + k];
    acc += hp[s * 32 + c];
  }
  acc += __shfl_xor(acc, 32, 64);
  float inv = 1.0f / fmaxf((float)dg, 1.0f);
  // lanes 0..31: mean-aggregated row; lanes 32..63: node's own hp row
  float rv = (lane < 32) ? acc * inv : hp[wid * 32 + c];
  float s1 = 0.f, s2 = 0.f;
#pragma unroll
  for (int k = 0; k < 32; ++k) {
    float a = __shfl(rv, k, 64);
    float h = __shfl(rv, 32 + k, 64);
    s1 += a * W2l[k * 64 + lane];
    s2 += h * W2r[k * 64 + lane];
  }
  float v = s1 + b2[lane] + s2;
  unsigned j = (unsigned)(wid * 64 + lane);
  float d = keep_bit(DK1.a, DK1.b, j) ? 2.0f * v : 0.0f;
  float ss = d * d;
#pragma unroll
  for (int o = 32; o > 0; o >>= 1) ss += __shfl_xor(ss, o, 64);
  float scale = 1.0f / fmaxf(sqrtf(ss), 1e-12f);
  out[j] = d * scale;
}

// --------------------------------------------------------------------------
extern "C" void kernel_launch(void* const* d_in, const int* in_sizes, int n_in,
                              void* d_out, int out_size, void* d_ws, size_t ws_size,
                              hipStream_t stream) {
  const float* x   = (const float*)d_in[0];
  const int*   ei  = (const int*)d_in[1];
  const float* W1l = (const float*)d_in[2];
  const float* b1  = (const float*)d_in[3];
  const float* W1r = (const float*)d_in[4];
  const float* W2l = (const float*)d_in[5];
  const float* b2  = (const float*)d_in[6];
  const float* W2r = (const float*)d_in[7];
  float* out = (float*)d_out;

  const int* src = ei;            // edge_index[0]
  const int* dst = ei + N_EDGES;  // edge_index[1]

  const size_t F32 = (size_t)N_NODES * 32;
  float* xl   = (float*)d_ws;                    // 12.8 MB
  float* xr   = xl + F32;                        // 12.8 MB
  float* hp   = xr + F32;                        // 12.8 MB
  int* deg    = (int*)(hp + F32);                // 400 KB
  int* offs   = deg + N_NODES;                   // 400 KB
  int* cursor = offs + N_NODES;                  // 400 KB
  int* eidx   = cursor + N_NODES;                // 6.4 MB  (total ~46 MB)

  hipMemsetAsync(deg, 0, (size_t)N_NODES * sizeof(int), stream);

  const int EB = (N_EDGES + 255) / 256;
  k_count<<<EB, 256, 0, stream>>>(dst, deg);
  k_scan<<<1, 1024, 0, stream>>>(deg, offs, cursor);
  k_fill<<<EB, 256, 0, stream>>>(src, dst, cursor, eidx);

  k_transform1<<<(N_NODES + 3) / 4, 256, 0, stream>>>(x, W1l, W1r, xl, xr);
  k_gather1<<<(N_NODES + 3) / 4, 256, 0, stream>>>(xl, xr, offs, deg, eidx, b1, hp);
  k_out<<<(N_NODES + 3) / 4, 256, 0, stream>>>(hp, offs, deg, eidx, W2l, b2, W2r, out);
}

// Round 4
// 475.075 us; speedup vs baseline: 1.3919x; 1.3358x over previous
//
#include <hip/hip_runtime.h>

#define N_NODES 100000
#define N_EDGES 1600000
#define SCAN_CHUNK 2048
#define SCAN_NBLK ((N_NODES + SCAN_CHUNK - 1) / SCAN_CHUNK)   // 49

// ---------------- JAX threefry2x32 (partitionable scheme) ----------------
struct U2 { unsigned a, b; };

__host__ __device__ constexpr U2 tf2x32(unsigned k0, unsigned k1, unsigned c0, unsigned c1) {
  unsigned ks2 = k0 ^ k1 ^ 0x1BD11BDAu;
  unsigned x0 = c0 + k0, x1 = c1 + k1;
#define TFR(r) { x0 += x1; x1 = (x1 << (r)) | (x1 >> (32 - (r))); x1 ^= x0; }
  TFR(13) TFR(15) TFR(26) TFR(6)
  x0 += k1;  x1 += ks2 + 1u;
  TFR(17) TFR(29) TFR(16) TFR(24)
  x0 += ks2; x1 += k0 + 2u;
  TFR(13) TFR(15) TFR(26) TFR(6)
  x0 += k0;  x1 += k1 + 3u;
  TFR(17) TFR(29) TFR(16) TFR(24)
  x0 += k1;  x1 += ks2 + 4u;
  TFR(13) TFR(15) TFR(26) TFR(6)
  x0 += ks2; x1 += k0 + 5u;
#undef TFR
  return U2{x0, x1};
}

constexpr U2 DK0 = tf2x32(0u, 42u, 0u, 0u);
constexpr U2 DK1 = tf2x32(0u, 42u, 0u, 1u);

__device__ __forceinline__ bool keep_bit(unsigned k0, unsigned k1, unsigned j) {
  U2 w = tf2x32(k0, k1, 0u, j);
  return ((w.a ^ w.b) >> 31) == 0u;
}

// ---------------- Kernel A: xl = x@W1_l, xr = x@W1_r (wave per row) -------
__global__ __launch_bounds__(256) void k_transform1(
    const float* __restrict__ x, const float* __restrict__ Wl,
    const float* __restrict__ Wr, float* __restrict__ xl,
    float* __restrict__ xr) {
  int wid = (int)((blockIdx.x * blockDim.x + threadIdx.x) >> 6);
  int lane = threadIdx.x & 63;
  if (wid >= N_NODES) return;
  float xv = x[wid * 64 + lane];
  const float* W = (lane < 32) ? Wl : Wr;
  int c = lane & 31;
  float s = 0.f;
#pragma unroll
  for (int k = 0; k < 64; ++k) {
    float b = __shfl(xv, k, 64);
    s += b * W[k * 32 + c];
  }
  if (lane < 32) xl[wid * 32 + c] = s;
  else           xr[wid * 32 + c] = s;
}

// ---------------- CSR build ----------------
__global__ __launch_bounds__(256) void k_count(
    const int* __restrict__ dst, int* __restrict__ deg) {
  int e = (int)(blockIdx.x * blockDim.x + threadIdx.x);
  if (e >= N_EDGES) return;
  atomicAdd(&deg[dst[e]], 1);
}

// --- hierarchical scan: (1) per-block sums, (2) scan partials, (3) write ---
__global__ __launch_bounds__(256) void k_scan1(
    const int* __restrict__ deg, int* __restrict__ partials) {
  __shared__ int ws[4];
  int t = threadIdx.x, lane = t & 63, w = t >> 6;
  long long gbase = (long long)blockIdx.x * SCAN_CHUNK;
  int s = 0;
#pragma unroll
  for (int i = 0; i < 8; ++i) {
    long long idx = gbase + i * 256 + t;
    s += (idx < N_NODES) ? deg[idx] : 0;
  }
#pragma unroll
  for (int o = 32; o > 0; o >>= 1) s += __shfl_xor(s, o, 64);
  if (lane == 0) ws[w] = s;
  __syncthreads();
  if (t == 0) partials[blockIdx.x] = ws[0] + ws[1] + ws[2] + ws[3];
}

__global__ __launch_bounds__(64) void k_scan2(
    const int* __restrict__ partials, int* __restrict__ pbase) {
  int lane = threadIdx.x;
  int v = (lane < SCAN_NBLK) ? partials[lane] : 0;
  int x = v;
#pragma unroll
  for (int o = 1; o < 64; o <<= 1) {
    int y = __shfl_up(x, o, 64);
    if (lane >= o) x += y;
  }
  if (lane < SCAN_NBLK) pbase[lane] = x - v;
}

__global__ __launch_bounds__(256) void k_scan3(
    const int* __restrict__ deg, const int* __restrict__ pbase,
    int* __restrict__ offs, int* __restrict__ cursor) {
  __shared__ int wsum[4];
  int t = threadIdx.x, lane = t & 63, w = t >> 6;
  long long gbase = (long long)blockIdx.x * SCAN_CHUNK;
  int v[8];
  int run = 0;
#pragma unroll
  for (int i = 0; i < 8; ++i) {
    long long idx = gbase + t * 8 + i;
    int xv = (idx < N_NODES) ? deg[idx] : 0;
    v[i] = run; run += xv;
  }
  int tot = run, x = tot;
#pragma unroll
  for (int o = 1; o < 64; o <<= 1) {
    int y = __shfl_up(x, o, 64);
    if (lane >= o) x += y;
  }
  int laneExcl = x - tot;
  if (lane == 63) wsum[w] = x;
  __syncthreads();
  int wbase = 0;
  for (int i = 0; i < w; ++i) wbase += wsum[i];
  int b = pbase[blockIdx.x] + wbase + laneExcl;
#pragma unroll
  for (int i = 0; i < 8; ++i) {
    long long idx = gbase + t * 8 + i;
    if (idx < N_NODES) { int e = b + v[i]; offs[idx] = e; cursor[idx] = e; }
  }
}

__global__ __launch_bounds__(256) void k_fill(
    const int* __restrict__ src, const int* __restrict__ dst,
    int* __restrict__ cursor, int* __restrict__ eidx) {
  int e = (int)(blockIdx.x * blockDim.x + threadIdx.x);
  if (e >= N_EDGES) return;
  int d = dst[e];
  int p = atomicAdd(&cursor[d], 1);
  eidx[p] = src[e];
}

// ---- Gather layer 1: hp = dropout(lrelu(mean(xl[nbrs]) + b1 + xr)) ------
// One wave per node, half-wave per edge. Per-lane broadcast loads of
// eidx[off+k] (same address across a half -> one fetch), unrolled 4x so
// 4 independent row loads are in flight. No cross-lane ops inside the
// (possibly divergent) loop — shfl_xor happens after reconvergence.
__global__ __launch_bounds__(256) void k_gather1(
    const float* __restrict__ xl, const float* __restrict__ xr,
    const int* __restrict__ offs, const int* __restrict__ deg,
    const int* __restrict__ eidx, const float* __restrict__ b1,
    float* __restrict__ hp) {
  int wid = (int)((blockIdx.x * blockDim.x + threadIdx.x) >> 6);
  int lane = threadIdx.x & 63;
  if (wid >= N_NODES) return;
  int c = lane & 31, half = lane >> 5;
  int off = offs[wid];
  int dg = deg[wid];
  float acc = 0.f;
  int k = half;
  for (; k + 6 < dg; k += 8) {
    int s0 = eidx[off + k];
    int s1 = eidx[off + k + 2];
    int s2 = eidx[off + k + 4];
    int s3 = eidx[off + k + 6];
    float a0 = xl[s0 * 32 + c];
    float a1 = xl[s1 * 32 + c];
    float a2 = xl[s2 * 32 + c];
    float a3 = xl[s3 * 32 + c];
    acc += a0; acc += a1; acc += a2; acc += a3;
  }
  for (; k < dg; k += 2) {
    int s = eidx[off + k];
    acc += xl[s * 32 + c];
  }
  acc += __shfl_xor(acc, 32, 64);
  if (lane < 32) {
    float inv = 1.0f / fmaxf((float)dg, 1.0f);
    int j = wid * 32 + c;
    float v = acc * inv + b1[c] + xr[j];
    v = (v > 0.f) ? v : 0.01f * v;
    hp[j] = keep_bit(DK0.a, DK0.b, (unsigned)j) ? 2.0f * v : 0.0f;
  }
}

// ---- Gather layer 2 fused with output GEMM + dropout + L2 norm ----------
__global__ __launch_bounds__(256) void k_out(
    const float* __restrict__ hp, const int* __restrict__ offs,
    const int* __restrict__ deg, const int* __restrict__ eidx,
    const float* __restrict__ W2l, const float* __restrict__ b2,
    const float* __restrict__ W2r, float* __restrict__ out) {
  int wid = (int)((blockIdx.x * blockDim.x + threadIdx.x) >> 6);
  int lane = threadIdx.x & 63;
  if (wid >= N_NODES) return;
  int c = lane & 31, half = lane >> 5;
  int off = offs[wid];
  int dg = deg[wid];
  float acc = 0.f;
  int k = half;
  for (; k + 6 < dg; k += 8) {
    int s0 = eidx[off + k];
    int s1 = eidx[off + k + 2];
    int s2 = eidx[off + k + 4];
    int s3 = eidx[off + k + 6];
    float a0 = hp[s0 * 32 + c];
    float a1 = hp[s1 * 32 + c];
    float a2 = hp[s2 * 32 + c];
    float a3 = hp[s3 * 32 + c];
    acc += a0; acc += a1; acc += a2; acc += a3;
  }
  for (; k < dg; k += 2) {
    int s = eidx[off + k];
    acc += hp[s * 32 + c];
  }
  acc += __shfl_xor(acc, 32, 64);
  float inv = 1.0f / fmaxf((float)dg, 1.0f);
  // lanes 0..31: mean-aggregated row; lanes 32..63: node's own hp row
  float rv = (lane < 32) ? acc * inv : hp[wid * 32 + c];
  float s1 = 0.f, s2 = 0.f;
#pragma unroll
  for (int kk = 0; kk < 32; ++kk) {
    float a = __shfl(rv, kk, 64);
    float h = __shfl(rv, 32 + kk, 64);
    s1 += a * W2l[kk * 64 + lane];
    s2 += h * W2r[kk * 64 + lane];
  }
  float v = s1 + b2[lane] + s2;
  unsigned j = (unsigned)(wid * 64 + lane);
  float d = keep_bit(DK1.a, DK1.b, j) ? 2.0f * v : 0.0f;
  float ss = d * d;
#pragma unroll
  for (int o = 32; o > 0; o >>= 1) ss += __shfl_xor(ss, o, 64);
  float scale = 1.0f / fmaxf(sqrtf(ss), 1e-12f);
  out[j] = d * scale;
}

// --------------------------------------------------------------------------
extern "C" void kernel_launch(void* const* d_in, const int* in_sizes, int n_in,
                              void* d_out, int out_size, void* d_ws, size_t ws_size,
                              hipStream_t stream) {
  const float* x   = (const float*)d_in[0];
  const int*   ei  = (const int*)d_in[1];
  const float* W1l = (const float*)d_in[2];
  const float* b1  = (const float*)d_in[3];
  const float* W1r = (const float*)d_in[4];
  const float* W2l = (const float*)d_in[5];
  const float* b2  = (const float*)d_in[6];
  const float* W2r = (const float*)d_in[7];
  float* out = (float*)d_out;

  const int* src = ei;            // edge_index[0]
  const int* dst = ei + N_EDGES;  // edge_index[1]

  const size_t F32 = (size_t)N_NODES * 32;
  float* xl    = (float*)d_ws;                   // 12.8 MB
  float* xr    = xl + F32;                       // 12.8 MB
  float* hp    = xr + F32;                       // 12.8 MB
  int* deg     = (int*)(hp + F32);               // 400 KB
  int* offs    = deg + N_NODES;                  // 400 KB
  int* cursor  = offs + N_NODES;                 // 400 KB
  int* eidx    = cursor + N_NODES;               // 6.4 MB
  int* partial = eidx + N_EDGES;                 // small
  int* pbase   = partial + SCAN_NBLK;

  hipMemsetAsync(deg, 0, (size_t)N_NODES * sizeof(int), stream);

  const int EB = (N_EDGES + 255) / 256;
  k_count<<<EB, 256, 0, stream>>>(dst, deg);
  k_scan1<<<SCAN_NBLK, 256, 0, stream>>>(deg, partial);
  k_scan2<<<1, 64, 0, stream>>>(partial, pbase);
  k_scan3<<<SCAN_NBLK, 256, 0, stream>>>(deg, pbase, offs, cursor);
  k_fill<<<EB, 256, 0, stream>>>(src, dst, cursor, eidx);

  k_transform1<<<(N_NODES + 3) / 4, 256, 0, stream>>>(x, W1l, W1r, xl, xr);
  k_gather1<<<(N_NODES + 3) / 4, 256, 0, stream>>>(xl, xr, offs, deg, eidx, b1, hp);
  k_out<<<(N_NODES + 3) / 4, 256, 0, stream>>>(hp, offs, deg, eidx, W2l, b2, W2r, out);
}